// Round 1
// baseline (468.869 us; speedup 1.0000x reference)
//
#include <hip/hip_runtime.h>
#include <math.h>

// SpatialAttention: x[16,224,224,256] f32 (NHWC)
//   max/mean over C -> [B,H,W,2] -> conv7x7(2->1, SAME) -> sigmoid -> x * attn
#define B_ 16
#define H_ 224
#define W_ 224
#define C_ 256
#define NPIX (B_*H_*W_)   // 802816 = 64 * 12544; H_*W_ = 50176 = 64*784

// ---------------- Kernel 1: per-pixel channel max & mean ----------------
// One wave64 per pixel. Lane i loads float4 at channel 4i (1 KB contiguous
// per wave -> perfectly coalesced). 6-level shuffle reduce.
__global__ __launch_bounds__(256) void pool_kernel(const float* __restrict__ x,
                                                   float2* __restrict__ pooled) {
    const int wave = threadIdx.x >> 6;
    const int lane = threadIdx.x & 63;
    const int pid  = blockIdx.x * 4 + wave;          // grid = NPIX/4, exact
    const float4* px = (const float4*)(x + (size_t)pid * C_);
    float4 v = px[lane];
    float m = fmaxf(fmaxf(v.x, v.y), fmaxf(v.z, v.w));
    float s = v.x + v.y + v.z + v.w;
    #pragma unroll
    for (int off = 1; off < 64; off <<= 1) {
        m = fmaxf(m, __shfl_xor(m, off));
        s += __shfl_xor(s, off);
    }
    if (lane == 0) pooled[pid] = make_float2(m, s * (1.0f / 256.0f));
}

// ------- Kernel 2: 7x7 conv + sigmoid + broadcast multiply (fused) -------
// Block = 256 threads handles 64 consecutive pixels.
// Phase 1: 4 threads per pixel split 49 taps, shuffle-reduce, sigmoid->LDS.
// Phase 2: 16 coalesced float4 iterations scaling x by attn.
__global__ __launch_bounds__(256) void attn_mul_kernel(const float* __restrict__ x,
                                                       const float2* __restrict__ pooled,
                                                       const float* __restrict__ cw,  // [7,7,2,1] -> flat (kh*7+kw)*2+c
                                                       const float* __restrict__ cb,
                                                       float* __restrict__ out) {
    __shared__ float sw[98];
    __shared__ float sbias;
    __shared__ float sattn[64];
    const int t = threadIdx.x;
    if (t < 98) sw[t] = cw[t];
    if (t == 98) sbias = cb[0];
    __syncthreads();

    const int p   = t >> 2;                 // pixel slot 0..63
    const int s   = t & 3;                  // tap-group 0..3
    const int pid = blockIdx.x * 64 + p;
    const int b   = pid / (H_ * W_);
    const int rem = pid % (H_ * W_);
    const int h   = rem / W_;
    const int w   = rem % W_;

    float acc = 0.0f;
    #pragma unroll
    for (int tap = 0; tap < 49; tap += 4) {
        const int tp = tap + s;             // s, s+4, ..., covers 0..48
        if (tp < 49) {
            const int kh = tp / 7, kw = tp % 7;
            const int hh = h + kh - 3, ww = w + kw - 3;
            if (hh >= 0 && hh < H_ && ww >= 0 && ww < W_) {
                const float2 pv = pooled[((size_t)b * H_ + hh) * W_ + ww];
                acc = fmaf(pv.x, sw[tp * 2],     acc);
                acc = fmaf(pv.y, sw[tp * 2 + 1], acc);
            }
        }
    }
    // reduce the 4 partials (adjacent lanes within a wave)
    acc += __shfl_xor(acc, 1);
    acc += __shfl_xor(acc, 2);
    if (s == 0) sattn[p] = 1.0f / (1.0f + expf(-(acc + sbias)));
    __syncthreads();

    const float4* xx = (const float4*)(x   + (size_t)blockIdx.x * 64 * C_);
    float4*       oo = (float4*)      (out + (size_t)blockIdx.x * 64 * C_);
    #pragma unroll
    for (int i = 0; i < 16; ++i) {
        const int idx = i * 256 + t;        // float4 index in block's 4096
        const float a = sattn[idx >> 6];    // 64 float4 per pixel
        float4 v = xx[idx];
        v.x *= a; v.y *= a; v.z *= a; v.w *= a;
        oo[idx] = v;
    }
}

extern "C" void kernel_launch(void* const* d_in, const int* in_sizes, int n_in,
                              void* d_out, int out_size, void* d_ws, size_t ws_size,
                              hipStream_t stream) {
    const float* x  = (const float*)d_in[0];
    const float* cw = (const float*)d_in[1];
    const float* cb = (const float*)d_in[2];
    float* out      = (float*)d_out;
    float2* pooled  = (float2*)d_ws;        // NPIX * 8 B = 6.4 MB

    pool_kernel<<<NPIX / 4, 256, 0, stream>>>(x, pooled);
    attn_mul_kernel<<<NPIX / 64, 256, 0, stream>>>(x, pooled, cw, cb, out);
}

// Round 3
// 435.754 us; speedup vs baseline: 1.0760x; 1.0760x over previous
//
#include <hip/hip_runtime.h>
#include <math.h>

// SpatialAttention: x[16,224,224,256] f32 (NHWC)
//   max/mean over C -> [B,H,W,2] -> conv7x7(2->1, SAME) -> sigmoid -> x * attn
#define B_ 16
#define H_ 224
#define W_ 224
#define C_ 256
#define NPIX (B_*H_*W_)   // 802816 = 16 * 50176
#define NROW (B_*H_)      // 3584 rows, % 8 == 0

typedef float f32x4 __attribute__((ext_vector_type(4)));

// ---------------- Kernel 1: per-pixel channel max & mean ----------------
// 16 lanes per pixel, 4 pixels per wave, 16 pixels per block.
// Lane `sub` of a group loads 4 float4s (each instr: 16 lanes x 16 B = 256 B
// contiguous, coalesced), accumulates locally, then 4-level shuffle reduce.
__global__ __launch_bounds__(256) void pool_kernel(const float* __restrict__ x,
                                                   float2* __restrict__ pooled) {
    const int t    = threadIdx.x;
    const int wave = t >> 6;
    const int lane = t & 63;
    const int grp  = lane >> 4;          // pixel within wave: 0..3
    const int sub  = lane & 15;          // lane within 16-group
    const int pid  = (blockIdx.x * 4 + wave) * 4 + grp;   // grid = NPIX/16 exact
    const f32x4* px = (const f32x4*)(x + (size_t)pid * C_);
    float m = -INFINITY, s = 0.0f;
    #pragma unroll
    for (int j = 0; j < 4; ++j) {
        f32x4 v = __builtin_nontemporal_load(&px[j * 16 + sub]);
        m = fmaxf(m, fmaxf(fmaxf(v.x, v.y), fmaxf(v.z, v.w)));
        s += (v.x + v.y) + (v.z + v.w);
    }
    #pragma unroll
    for (int off = 1; off < 16; off <<= 1) {
        m = fmaxf(m, __shfl_xor(m, off));
        s += __shfl_xor(s, off);
    }
    if (sub == 0) pooled[pid] = make_float2(m, s * (1.0f / 256.0f));
}

// ---- Kernel 2: one block per image row: LDS-staged conv + stream mul ----
__global__ __launch_bounds__(256) void attn_row_kernel(const float* __restrict__ x,
                                                       const float2* __restrict__ pooled,
                                                       const float* __restrict__ cw,  // [7,7,2,1]
                                                       const float* __restrict__ cb,
                                                       float* __restrict__ out) {
    __shared__ float2 spool[7][232];     // rows h-3..h+3, cols -3..226 (zero-padded)
    __shared__ float2 sw2[49];           // (kh*7+kw) -> (w_max, w_avg)
    __shared__ float  sbias;
    __shared__ float  sattn[224];

    const int t   = threadIdx.x;
    const int bid = blockIdx.x;
    // XCD-chunked swizzle: each XCD gets a contiguous run of rows (3584 % 8 == 0)
    const int row = (bid & 7) * (NROW / 8) + (bid >> 3);
    const int b   = row / H_;
    const int h   = row % H_;

    if (t < 98)  ((float*)sw2)[t] = cw[t];
    if (t == 98) sbias = cb[0];

    // stage pooled halo: 7 rows x 230 cols, zero-filled outside the image
    const float2* prow = pooled + (size_t)b * (H_ * W_);
    for (int idx = t; idx < 7 * 230; idx += 256) {
        const int r  = idx / 230;
        const int ci = idx % 230;        // 0..229 -> col ci-3
        const int hh = h - 3 + r;
        const int c  = ci - 3;
        float2 v = make_float2(0.0f, 0.0f);
        if (hh >= 0 && hh < H_ && c >= 0 && c < W_) v = prow[hh * W_ + c];
        spool[r][ci] = v;
    }
    __syncthreads();

    // conv 7x7 (2ch) + sigmoid, one thread per pixel of the row
    if (t < W_) {
        float acc = 0.0f;
        #pragma unroll
        for (int kh = 0; kh < 7; ++kh) {
            #pragma unroll
            for (int kw = 0; kw < 7; ++kw) {
                const float2 pv = spool[kh][t + kw];
                const float2 wv = sw2[kh * 7 + kw];
                acc = fmaf(pv.x, wv.x, fmaf(pv.y, wv.y, acc));
            }
        }
        sattn[t] = 1.0f / (1.0f + expf(-(acc + sbias)));
    }
    __syncthreads();

    // stream: scale the row's 224*256 floats = 14336 float4
    const f32x4* xx = (const f32x4*)(x   + (size_t)row * W_ * C_);
    f32x4*       oo = (f32x4*)      (out + (size_t)row * W_ * C_);
    #pragma unroll 4
    for (int i = 0; i < 56; ++i) {
        const int idx = i * 256 + t;
        const float a = sattn[idx >> 6];         // wave-uniform -> LDS broadcast
        f32x4 v = __builtin_nontemporal_load(&xx[idx]);
        v.x *= a; v.y *= a; v.z *= a; v.w *= a;
        __builtin_nontemporal_store(v, &oo[idx]);
    }
}

extern "C" void kernel_launch(void* const* d_in, const int* in_sizes, int n_in,
                              void* d_out, int out_size, void* d_ws, size_t ws_size,
                              hipStream_t stream) {
    const float* x  = (const float*)d_in[0];
    const float* cw = (const float*)d_in[1];
    const float* cb = (const float*)d_in[2];
    float* out      = (float*)d_out;
    float2* pooled  = (float2*)d_ws;        // NPIX * 8 B = 6.4 MB

    pool_kernel<<<NPIX / 16, 256, 0, stream>>>(x, pooled);
    attn_row_kernel<<<NROW, 256, 0, stream>>>(x, pooled, cw, cb, out);
}